// Round 1
// 1376.477 us; speedup vs baseline: 1.4623x; 1.4623x over previous
//
#include <hip/hip_runtime.h>
#include <hip/hip_bf16.h>

#define NNODES 1000000
#define NB 2000
#define BN_EPS 1e-5f

typedef __bf16 bf16x8 __attribute__((ext_vector_type(8)));
typedef float f32x4 __attribute__((ext_vector_type(4)));

__device__ __forceinline__ unsigned bf16rne(float f) {
    unsigned u = __builtin_bit_cast(unsigned, f);
    return (u + 0x7fffu + ((u >> 16) & 1u)) >> 16;
}
__device__ __forceinline__ unsigned pk2(float a, float b) {
    return bf16rne(a) | (bf16rne(b) << 16);
}
__device__ __forceinline__ float blo(unsigned u) {
    return __builtin_bit_cast(float, u << 16);
}
__device__ __forceinline__ float bhi(unsigned u) {
    return __builtin_bit_cast(float, u & 0xffff0000u);
}

// ---------------- kernel 1: graph boundaries + zero BN stats ----------------
__global__ __launch_bounds__(256) void k_bounds(const int* __restrict__ batch,
                                                int* __restrict__ start,
                                                float* __restrict__ stats) {
    int g = blockIdx.x * 256 + threadIdx.x;
    if (g < 256) stats[g] = 0.f;          // [0:128]=sum, [128:256]=sumsq
    if (g > NB) return;
    if (g == NB) { start[g] = NNODES; return; }
    int lo = 0, hi = NNODES;
    while (lo < hi) {
        int mid = (lo + hi) >> 1;
        if (batch[mid] < g) lo = mid + 1; else hi = mid;
    }
    start[g] = lo;
}

// -------- weight prep: pack W[k][J] f32 into per-lane bf16 A-fragments ------
// frag = jt*2 + ks; lane l: m = l&15 (j-offset), k = ks*32 + (l>>4)*8 + i
__global__ __launch_bounds__(256) void k_wprep(const float* __restrict__ W,
                                               uint4* __restrict__ wp, int J) {
    int t = blockIdx.x * 256 + threadIdx.x;
    int nfrag = (J >> 4) * 2;
    int frag = t >> 6, l = t & 63;
    if (frag >= nfrag) return;
    int jt = frag >> 1, ks = frag & 1;
    int j = jt * 16 + (l & 15);
    int k0 = ks * 32 + ((l >> 4) << 3);
    float v[8];
    #pragma unroll
    for (int i = 0; i < 8; ++i) v[i] = W[(size_t)(k0 + i) * J + j];
    uint4 o;
    o.x = pk2(v[0], v[1]); o.y = pk2(v[2], v[3]);
    o.z = pk2(v[4], v[5]); o.w = pk2(v[6], v[7]);
    wp[frag * 64 + l] = o;
}

// ------- kernel 2: h1[n][64] = relu(x0 @ W0 + b0), bf16 node-major ----------
__global__ __launch_bounds__(256) void k_h1(const float* __restrict__ pp,
                                            const float* __restrict__ W0,
                                            const float* __restrict__ b0,
                                            __hip_bfloat16* __restrict__ h1) {
    __shared__ float w0t[64 * 16];  // [j][k], conflict-free staging
    __shared__ float b0s[64];
    int tid = threadIdx.x;
    for (int idx = tid; idx < 1024; idx += 256) {
        int j = idx >> 4, k = idx & 15;
        w0t[idx] = W0[k * 64 + j];
    }
    if (tid < 64) b0s[tid] = b0[tid];
    __syncthreads();
    int n = blockIdx.x * 256 + tid;
    if (n >= NNODES) return;
    float xk[16];
    const float2* pp2 = (const float2*)pp;
    #pragma unroll
    for (int f = 0; f < 8; ++f) {
        float2 v = pp2[(size_t)f * NNODES + n];
        xk[2 * f] = v.x; xk[2 * f + 1] = v.y;
    }
    uint4* dst = (uint4*)(h1 + (size_t)n * 64);
    #pragma unroll
    for (int q = 0; q < 8; ++q) {
        float r[8];
        #pragma unroll
        for (int jj = 0; jj < 8; ++jj) {
            int j = q * 8 + jj;
            float acc = b0s[j];
            const float4* wr = (const float4*)&w0t[j * 16];
            #pragma unroll
            for (int k4 = 0; k4 < 4; ++k4) {
                float4 w = wr[k4];
                acc += xk[4*k4]*w.x + xk[4*k4+1]*w.y + xk[4*k4+2]*w.z + xk[4*k4+3]*w.w;
            }
            r[jj] = fmaxf(acc, 0.f);
        }
        uint4 o;
        o.x = pk2(r[0], r[1]); o.y = pk2(r[2], r[3]);
        o.z = pk2(r[4], r[5]); o.w = pk2(r[6], r[7]);
        dst[q] = o;
    }
}

// ---- kernel 3/5: xm'[g][j] = mean_g(h) @ lw - gb   (block per graph) -------
// h is node-major [n][64]; fully coalesced row reads.
__global__ __launch_bounds__(256) void k_xm(const __hip_bfloat16* __restrict__ h,
                                            const int* __restrict__ start,
                                            const float* __restrict__ lw,
                                            const float* __restrict__ gb,
                                            float* __restrict__ xm, int J) {
    __shared__ float part[4][64];
    __shared__ float meanv[64];
    int g = blockIdx.x;
    int s = start[g], e = start[g + 1];
    int tid = threadIdx.x;
    int p = tid & 31, slice = tid >> 5;   // feature-pair, node slice 0..7
    const unsigned* h32 = (const unsigned*)h;
    float s0 = 0.f, s1 = 0.f;
    for (int n = s + slice; n < e; n += 8) {
        unsigned u = h32[(size_t)n * 32 + p];
        s0 += blo(u); s1 += bhi(u);
    }
    s0 += __shfl_xor(s0, 32, 64);
    s1 += __shfl_xor(s1, 32, 64);
    int wave = tid >> 6, lane = tid & 63;
    if (lane < 32) { part[wave][2 * p] = s0; part[wave][2 * p + 1] = s1; }
    __syncthreads();
    if (tid < 64) {
        float inv = 1.f / fmaxf((float)(e - s), 1.f);
        meanv[tid] = (part[0][tid] + part[1][tid] + part[2][tid] + part[3][tid]) * inv;
    }
    __syncthreads();
    for (int j = tid; j < J; j += 256) {
        float acc = -gb[j];
        #pragma unroll 8
        for (int k = 0; k < 64; ++k) acc += meanv[k] * lw[k * J + j];
        xm[(size_t)g * J + j] = acc;
    }
}

// ------- kernels 4/6: hout[n][J] = relu(hin @ W - xm'[batch[n]]) via MFMA ----
// per wave: 4 node-tiles of 16 nodes; per tile: NJT j-tiles x 2 k-steps MFMA.
template<int J>
__global__ __launch_bounds__(256) void k_layer(const __hip_bfloat16* __restrict__ hin,
                                               const int* __restrict__ batch,
                                               const uint4* __restrict__ wp,
                                               const float* __restrict__ xm,
                                               __hip_bfloat16* __restrict__ hout) {
    constexpr int NJT = J / 16;
    constexpr int NFRAG = NJT * 2;
    int tid = threadIdx.x;
    int lane = tid & 63, wave = tid >> 6;
    uint4 a[NFRAG];
    #pragma unroll
    for (int f = 0; f < NFRAG; ++f) a[f] = wp[f * 64 + lane];
    int colg = lane >> 4;                 // k-group for B, row-group for C
    int nbase = blockIdx.x * 256 + wave * 64 + (lane & 15);
    #pragma unroll
    for (int nt = 0; nt < 4; ++nt) {
        int n = nbase + nt * 16;
        bool valid = n < NNODES;
        int nn = valid ? n : (NNODES - 1);
        const uint4* hrow = (const uint4*)(hin + (size_t)nn * 64);
        uint4 b0 = hrow[colg];            // k = colg*8 .. +7
        uint4 b1 = hrow[colg + 4];        // k = 32 + colg*8 .. +7
        f32x4 acc[NJT];
        #pragma unroll
        for (int jt = 0; jt < NJT; ++jt) {
            f32x4 c = {0.f, 0.f, 0.f, 0.f};
            c = __builtin_amdgcn_mfma_f32_16x16x32_bf16(
                    __builtin_bit_cast(bf16x8, a[jt * 2]),
                    __builtin_bit_cast(bf16x8, b0), c, 0, 0, 0);
            c = __builtin_amdgcn_mfma_f32_16x16x32_bf16(
                    __builtin_bit_cast(bf16x8, a[jt * 2 + 1]),
                    __builtin_bit_cast(bf16x8, b1), c, 0, 0, 0);
            acc[jt] = c;
        }
        int g = batch[nn];
        const float* xr = &xm[(size_t)g * J + (colg << 2)];
        unsigned* orow = (unsigned*)(hout + (size_t)nn * J);
        #pragma unroll
        for (int jt = 0; jt < NJT; ++jt) {
            float4 xv = *(const float4*)&xr[jt * 16];
            float r0 = fmaxf(acc[jt][0] - xv.x, 0.f);
            float r1 = fmaxf(acc[jt][1] - xv.y, 0.f);
            float r2 = fmaxf(acc[jt][2] - xv.z, 0.f);
            float r3 = fmaxf(acc[jt][3] - xv.w, 0.f);
            if (valid) {
                int jbase = jt * 16 + (colg << 2);
                uint2 st; st.x = pk2(r0, r1); st.y = pk2(r2, r3);
                *(uint2*)&orow[jbase >> 1] = st;
            }
        }
    }
}

// ---------------- kernel 7: BN sum / sumsq per feature (node-major) ----------
__global__ __launch_bounds__(256) void k_bnstats(const __hip_bfloat16* __restrict__ v,
                                                 float* __restrict__ stats) {
    int tid = threadIdx.x;
    int lane = tid & 63, wave = tid >> 6;
    const unsigned* v32 = (const unsigned*)v;
    float s0 = 0.f, s1 = 0.f, q0 = 0.f, q1 = 0.f;
    for (int n = blockIdx.x * 4 + wave; n < NNODES; n += gridDim.x * 4) {
        unsigned u = v32[(size_t)n * 64 + lane];   // wave reads one full row
        float a = blo(u), b = bhi(u);
        s0 += a; s1 += b; q0 += a * a; q1 += b * b;
    }
    __shared__ float red[4][256];
    red[wave][2 * lane] = s0;
    red[wave][2 * lane + 1] = s1;
    red[wave][128 + 2 * lane] = q0;
    red[wave][129 + 2 * lane] = q1;
    __syncthreads();
    float t = red[0][tid] + red[1][tid] + red[2][tid] + red[3][tid];
    atomicAdd(&stats[tid], t);
}

// ---------------- kernel 8: finalize scale/shift -----------------------------
__global__ void k_bnfinal(const float* __restrict__ stats,
                          const float* __restrict__ gamma,
                          const float* __restrict__ beta,
                          float* __restrict__ ss) {
    int j = threadIdx.x;
    if (j < 128) {
        float mean = stats[j] * (1.f / NNODES);
        float var = stats[128 + j] * (1.f / NNODES) - mean * mean;
        float sc = gamma[j] * rsqrtf(var + BN_EPS);
        ss[j] = sc;
        ss[128 + j] = beta[j] - mean * sc;
    }
}

// ------- kernel 9: out = x + scale*v + shift (pure streaming, node-major) ----
__global__ __launch_bounds__(256) void k_out(const __hip_bfloat16* __restrict__ v,
                                             const float* __restrict__ x,
                                             const float* __restrict__ ss,
                                             float* __restrict__ out) {
    int t = blockIdx.x * 256 + threadIdx.x;
    int c0 = (t * 4) & 127;               // invariant across grid-stride iters
    float4 sc = *(const float4*)&ss[c0];
    float4 sh = *(const float4*)&ss[128 + c0];
    const uint2* v2 = (const uint2*)v;
    const float4* x4 = (const float4*)x;
    float4* o4 = (float4*)out;
    const size_t total = (size_t)NNODES * 32;   // in float4 units
    size_t stride = (size_t)gridDim.x * 256;
    for (size_t i = t; i < total; i += stride) {
        uint2 u = v2[i];
        float4 xv = x4[i];
        float4 r;
        r.x = xv.x + sc.x * blo(u.x) + sh.x;
        r.y = xv.y + sc.y * bhi(u.x) + sh.y;
        r.z = xv.z + sc.z * blo(u.y) + sh.z;
        r.w = xv.w + sc.w * bhi(u.y) + sh.w;
        o4[i] = r;
    }
}

extern "C" void kernel_launch(void* const* d_in, const int* in_sizes, int n_in,
                              void* d_out, int out_size, void* d_ws, size_t ws_size,
                              hipStream_t stream) {
    const float* x     = (const float*)d_in[0];
    const float* pp    = (const float*)d_in[1];
    const int*   batch = (const int*)d_in[2];
    const float* W0    = (const float*)d_in[3];
    const float* b0    = (const float*)d_in[4];
    const float* g1w   = (const float*)d_in[5];
    const float* g1b   = (const float*)d_in[6];
    const float* l1w   = (const float*)d_in[7];
    const float* g2w   = (const float*)d_in[8];
    const float* g2b   = (const float*)d_in[9];
    const float* l2w   = (const float*)d_in[10];
    const float* bng   = (const float*)d_in[11];
    const float* bnb   = (const float*)d_in[12];
    float* out = (float*)d_out;

    char* ws = (char*)d_ws;
    size_t o = 0;
    __hip_bfloat16* h1 = (__hip_bfloat16*)(ws + o); o += (size_t)64 * NNODES * 2;
    __hip_bfloat16* h2 = (__hip_bfloat16*)(ws + o); o += (size_t)64 * NNODES * 2;
    __hip_bfloat16* v  = (__hip_bfloat16*)(ws + o); o += (size_t)128 * NNODES * 2;
    int*   start = (int*)(ws + o);   o += 16384;
    float* xm1   = (float*)(ws + o); o += (size_t)NB * 64 * 4;
    float* xm2   = (float*)(ws + o); o += (size_t)NB * 128 * 4;
    float* stats = (float*)(ws + o); o += 1024;
    float* ss    = (float*)(ws + o); o += 1024;
    uint4* wp1   = (uint4*)(ws + o); o += 8 * 64 * 16;     // J=64: 8 frags
    uint4* wp2   = (uint4*)(ws + o); o += 16 * 64 * 16;    // J=128: 16 frags

    int nblk = (NNODES + 255) / 256;
    k_bounds<<<8, 256, 0, stream>>>(batch, start, stats);
    k_wprep<<<2, 256, 0, stream>>>(g1w, wp1, 64);
    k_wprep<<<4, 256, 0, stream>>>(g2w, wp2, 128);
    k_h1<<<nblk, 256, 0, stream>>>(pp, W0, b0, h1);
    k_xm<<<NB, 256, 0, stream>>>(h1, start, l1w, g1b, xm1, 64);
    k_layer<64><<<nblk, 256, 0, stream>>>(h1, batch, wp1, xm1, h2);
    k_xm<<<NB, 256, 0, stream>>>(h2, start, l2w, g2b, xm2, 128);
    k_layer<128><<<nblk, 256, 0, stream>>>(h2, batch, wp2, xm2, v);
    k_bnstats<<<2048, 256, 0, stream>>>(v, stats);
    k_bnfinal<<<1, 128, 0, stream>>>(stats, bng, bnb, ss);
    k_out<<<2048, 256, 0, stream>>>(v, x, ss, out);
}